// Round 10
// baseline (10409.859 us; speedup 1.0000x reference)
//
#include <hip/hip_runtime.h>
#include <math.h>

#define T 128
#define B 128
#define H 256
#define I 256
#define G4 1024  // 4*H
#define NB 2     // batch elements per block

typedef unsigned short u16;
typedef unsigned int u32;
typedef _Float16 half_t;
typedef _Float16 half2_t __attribute__((ext_vector_type(2)));

#if defined(__has_builtin)
#if __has_builtin(__builtin_amdgcn_fdot2)
#define HAS_FDOT2 1
#endif
#endif

__device__ __forceinline__ float fdot2(half2_t a, half2_t b, float c) {
#ifdef HAS_FDOT2
    return __builtin_amdgcn_fdot2(a, b, c, false);
#else
    return fmaf((float)a.x, (float)b.x, fmaf((float)a.y, (float)b.y, c));
#endif
}
__device__ __forceinline__ half2_t h2cast(u32 u) { return __builtin_bit_cast(half2_t, u); }

__device__ __forceinline__ float sigmoid_fast(float x) {
    return 1.0f / (1.0f + __expf(-x));
}
__device__ __forceinline__ float tanh_fast(float x) {
    x = fminf(fmaxf(x, -15.f), 15.f);
    const float e = __expf(2.0f * x);
    return (e - 1.0f) / (e + 1.0f);
}

// LDS-only barrier: drain lgkmcnt (ds_write visibility), s_barrier, but DO NOT
// drain vmcnt — register-destined global loads (weights, G rows) stay in flight
// across the barrier. No sched_barrier: leave the compiler free to schedule
// (round-9 lesson: order-pinning regressed 2x). Safe here because all
// cross-thread communication goes through LDS; global stores are never read back.
#define BARL() do {                                        \
    asm volatile("s_waitcnt lgkmcnt(0)" ::: "memory");     \
    __builtin_amdgcn_s_barrier();                          \
} while (0)

// ---------------- weight repack (one-shot, fp16 k-pair-major == coalesced) ----------------
// WhH[k2][o] = half2{Whh[o][2k2], Whh[o][2k2+1]},  k2<128, o<1024
__global__ void pack_whH(const float* __restrict__ Whh, half2_t* __restrict__ WhH) {
    const int k2 = blockIdx.x;      // 0..127
    const int o  = threadIdx.x;     // 0..1023
    half2_t v;
    v.x = (half_t)Whh[(size_t)o * H + 2 * k2];
    v.y = (half_t)Whh[(size_t)o * H + 2 * k2 + 1];
    WhH[(size_t)k2 * G4 + o] = v;
}
// WaH[k2][j] = half2{Wa[j][2k2], Wa[j][2k2+1]},  k2<256, j<256
__global__ void pack_waH(const float* __restrict__ Wa, half2_t* __restrict__ WaH) {
    const int k2 = blockIdx.x;      // 0..255
    const int j  = threadIdx.x;     // 0..255
    half2_t v;
    v.x = (half_t)Wa[(size_t)j * (2 * H) + 2 * k2];
    v.y = (half_t)Wa[(size_t)j * (2 * H) + 2 * k2 + 1];
    WaH[(size_t)k2 * H + j] = v;
}

// ---------------- G = embs @ Wih^T + bih + bhh ----------------
__global__ __launch_bounds__(256) void gemm_g(const float* __restrict__ A,
                                              const float* __restrict__ W,
                                              const float* __restrict__ bih,
                                              const float* __restrict__ bhh,
                                              float* __restrict__ G) {
    __shared__ __align__(16) float As[64][68];
    __shared__ __align__(16) float Ws[64][68];
    const int m0 = blockIdx.x * 64;
    const int n0 = blockIdx.y * 64;
    const int tid = threadIdx.x;
    const int ty = tid >> 4, tx = tid & 15;
    const int rr = tid >> 4;
    const int kr = tid & 15;

    float acc[4][4] = {};
    for (int k0 = 0; k0 < I; k0 += 64) {
#pragma unroll
        for (int i = 0; i < 4; ++i) {
            const int r = rr + 16 * i;
            const float4 av = *(const float4*)&A[(size_t)(m0 + r) * I + k0 + kr * 4];
            const float4 wv = *(const float4*)&W[(size_t)(n0 + r) * I + k0 + kr * 4];
            As[kr * 4 + 0][r] = av.x; As[kr * 4 + 1][r] = av.y;
            As[kr * 4 + 2][r] = av.z; As[kr * 4 + 3][r] = av.w;
            Ws[kr * 4 + 0][r] = wv.x; Ws[kr * 4 + 1][r] = wv.y;
            Ws[kr * 4 + 2][r] = wv.z; Ws[kr * 4 + 3][r] = wv.w;
        }
        __syncthreads();
#pragma unroll 8
        for (int kk = 0; kk < 64; ++kk) {
            const float4 a4 = *(const float4*)&As[kk][ty * 4];
            const float4 w4 = *(const float4*)&Ws[kk][tx * 4];
            const float a[4] = {a4.x, a4.y, a4.z, a4.w};
            const float w[4] = {w4.x, w4.y, w4.z, w4.w};
#pragma unroll
            for (int i = 0; i < 4; ++i)
#pragma unroll
                for (int jj = 0; jj < 4; ++jj)
                    acc[i][jj] = fmaf(a[i], w[jj], acc[i][jj]);
        }
        __syncthreads();
    }
    const int n = n0 + tx * 4;
    const float4 bi = *(const float4*)&bih[n];
    const float4 bh = *(const float4*)&bhh[n];
    const float4 bb = make_float4(bi.x + bh.x, bi.y + bh.y, bi.z + bh.z, bi.w + bh.w);
#pragma unroll
    for (int i = 0; i < 4; ++i) {
        const int m = m0 + ty * 4 + i;
        float4 o = make_float4(acc[i][0] + bb.x, acc[i][1] + bb.y,
                               acc[i][2] + bb.z, acc[i][3] + bb.w);
        *(float4*)&G[(size_t)m * G4 + n] = o;
    }
}

// ---------------- recurrent attention-LSTM: NB=2, fdot2, LDS-only barriers ----------------
// LDS: hid 131072 + sc 1024 + hH 1024 + hcI 2048 + hinI 1024 + red 8192 + gate 8192
//      = 152576 B <= 163840 (1 block/CU, 16 waves)
__global__ __launch_bounds__(1024, 4) void alstm6(
    const int* __restrict__ lens,
    const float* __restrict__ G,       // [T*B][4H]
    const half2_t* __restrict__ WhH,   // [128][1024] k2-major
    const half2_t* __restrict__ WaH,   // [256][256]  k2-major
    const float* __restrict__ ba,
    float* __restrict__ out)           // hs | h_fin | c_fin
{
    __shared__ __align__(16) half_t hid_s[NB][T][H];   // fp16 history, 128 KB
    __shared__ __align__(16) float  sc_s[NB][T];
    __shared__ __align__(16) half_t hH_s[NB][H];       // h (for scores)
    __shared__ __align__(16) half_t hcI_s[4 * 256];    // [h|ctx], batch-interleaved k-pairs
    __shared__ __align__(16) half_t hinI_s[4 * 128];   // hin, batch-interleaved k-pairs
    __shared__ __align__(16) float  red_s[2048];       // phase-reuse reduce buffer
    __shared__ __align__(16) float  gate_s[NB][G4];    // prefetched G rows

    const int b0 = blockIdx.x * NB;
    const int tid = threadIdx.x;
    const int lane = tid & 63;
    const int wave = tid >> 6;        // 0..15
    const int sb = wave >> 3;         // scores batch
    const int stp0 = wave & 7;        // scores t'-stride id
    const int cb = tid >> 9;          // ctx batch
    const int ck = (tid >> 8) & 1;    // ctx 2-way t-split
    const int cj = tid & 255;         // ctx feature
    const int ako = tid >> 8;         // Wa k-chunk 0..3
    const int aj = tid & 255;         // Wa output j
    const int eb = tid >> 8;          // cell batch (valid under tid<512)
    const int ej = tid & 255;         // cell feature

    const int len0 = lens[b0], len1 = lens[b0 + 1];
    float c_reg = 0.f;
    float* hfin = out + (size_t)T * B * H;
    float* cfin = hfin + (size_t)B * H;
    if (tid < 512) hH_s[eb][ej] = (half_t)0.f;

    const half2_t* wap = &WaH[(size_t)(ako * 64) * H + aj];  // Wa stream: stride H half2, coalesced
    const half2_t* whp = &WhH[tid];                          // Whh stream: stride G4 half2, coalesced

    BARL();

    for (int t = 0; t < T; ++t) {
        // ---- G-row prefetch into regs (in flight across barriers; stashed in ctx phase) ----
        const float gA = G[((size_t)t * B + b0) * G4 + tid];
        const float gB = G[((size_t)t * B + b0 + 1) * G4 + tid];
        half2_t whb[8];  // Whh rolling prefetch buffer

        if (t > 0) {
            // ---- P0: scores (8 waves per batch, t' strided) ----
            {
                const half2_t h2a = h2cast(*(const u32*)&hH_s[sb][lane * 4]);
                const half2_t h2b = h2cast(*(const u32*)&hH_s[sb][lane * 4 + 2]);
                for (int tp = stp0; tp < t; tp += 8) {
                    const uint2 hv = *(const uint2*)&hid_s[sb][tp][lane * 4];
                    float d = fdot2(h2cast(hv.x), h2a, fdot2(h2cast(hv.y), h2b, 0.f));
#pragma unroll
                    for (int off = 32; off; off >>= 1) d += __shfl_xor(d, off);
                    if (lane == 0) sc_s[sb][tp] = d;
                }
            }
            BARL();  // A
            // ---- P1: softmax (wave 0 -> batch 0, wave 8 -> batch 1) ----
            if (stp0 == 0) {
                const float v0 = (lane < t) ? sc_s[sb][lane] : -3.0e38f;
                const float v1 = (lane + 64 < t) ? sc_s[sb][lane + 64] : -3.0e38f;
                float m = fmaxf(v0, v1);
#pragma unroll
                for (int off = 32; off; off >>= 1) m = fmaxf(m, __shfl_xor(m, off));
                const float e0 = (lane < t) ? __expf(v0 - m) : 0.f;
                const float e1 = (lane + 64 < t) ? __expf(v1 - m) : 0.f;
                float s = e0 + e1;
#pragma unroll
                for (int off = 32; off; off >>= 1) s += __shfl_xor(s, off);
                const float inv = 1.f / s;
                if (lane < t) sc_s[sb][lane] = e0 * inv;
                if (lane + 64 < t) sc_s[sb][lane + 64] = e1 * inv;
            }
            BARL();  // B
            // ---- P2: ctx partials (2-way t-split per batch) + G stash ----
            {
                float cacc = 0.f;
                for (int tp = ck; tp < t; tp += 2)
                    cacc = fmaf(sc_s[cb][tp], (float)hid_s[cb][tp][cj], cacc);
                red_s[cb * 512 + ck * 256 + cj] = cacc;
                gate_s[0][tid] = gA;
                gate_s[1][tid] = gB;
            }
            BARL();  // C
            // ---- P3a: ctx reduce -> hcI; prefetch Wa weights (issued pre-barrier) ----
            half2_t wab[8];
            if (tid < 512) {
                const float ctxv = red_s[eb * 512 + ej] + red_s[eb * 512 + 256 + ej];
                hcI_s[512 + 4 * (ej >> 1) + 2 * eb + (ej & 1)] = (half_t)ctxv;
            }
#pragma unroll
            for (int p = 0; p < 8; ++p) wab[p] = wap[(size_t)p * H];
            BARL();  // D
            // ---- P3: Wa GEMV (rolling 8-deep prefetch, coalesced stream) ----
            {
                float a0 = 0.f, a1 = 0.f;
#pragma unroll
                for (int kk = 0; kk < 64; ++kk) {
                    const half2_t w = wab[kk & 7];
                    if (kk + 8 < 64) wab[kk & 7] = wap[(size_t)(kk + 8) * H];
                    const uint2 hh = *(const uint2*)&hcI_s[4 * (ako * 64 + kk)];
                    a0 = fdot2(w, h2cast(hh.x), a0);
                    a1 = fdot2(w, h2cast(hh.y), a1);
                }
                red_s[ako * 512 + aj] = a0;
                red_s[ako * 512 + 256 + aj] = a1;
            }
            BARL();  // E
            // ---- P4: hin reduce + tanh; prefetch Whh weights (issued pre-barrier) ----
            if (tid < 512) {
                float a = ba[ej];
#pragma unroll
                for (int r = 0; r < 4; ++r) a += red_s[r * 512 + eb * 256 + ej];
                hinI_s[4 * (ej >> 1) + 2 * eb + (ej & 1)] = (half_t)tanh_fast(a);
            }
#pragma unroll
            for (int p = 0; p < 8; ++p) whb[p] = whp[(size_t)p * G4];
            BARL();  // F
        } else {
            gate_s[0][tid] = gA;
            gate_s[1][tid] = gB;
            if (tid < 512) hinI_s[tid] = (half_t)0.f;
#pragma unroll
            for (int p = 0; p < 8; ++p) whb[p] = whp[(size_t)p * G4];
            BARL();
        }
        // ---- P5: Whh GEMV (one output o=tid, both batches, rolling prefetch) ----
        {
            float g0 = 0.f, g1 = 0.f;
#pragma unroll
            for (int k2 = 0; k2 < 128; ++k2) {
                const half2_t w = whb[k2 & 7];
                if (k2 + 8 < 128) whb[k2 & 7] = whp[(size_t)(k2 + 8) * G4];
                const uint2 hh = *(const uint2*)&hinI_s[4 * k2];
                g0 = fdot2(w, h2cast(hh.x), g0);
                g1 = fdot2(w, h2cast(hh.y), g1);
            }
            red_s[tid] = g0;
            red_s[1024 + tid] = g1;
        }
        BARL();  // G
        // ---- P6: gate sum + cell update (threads 0..511) ----
        if (tid < 512) {
            const int bg = b0 + eb;
            const float gi = gate_s[eb][ej]         + red_s[eb * 1024 + ej];
            const float gf = gate_s[eb][H + ej]     + red_s[eb * 1024 + H + ej];
            const float gg = gate_s[eb][2 * H + ej] + red_s[eb * 1024 + 2 * H + ej];
            const float go = gate_s[eb][3 * H + ej] + red_s[eb * 1024 + 3 * H + ej];
            const float ig = sigmoid_fast(gi);
            const float fg = sigmoid_fast(gf);
            const float gv = tanh_fast(gg);
            const float og = sigmoid_fast(go);
            c_reg = fmaf(fg, c_reg, ig * gv);
            const float h_new = og * tanh_fast(c_reg);
            const half_t hh = (half_t)h_new;
            hH_s[eb][ej] = hh;
            hid_s[eb][t][ej] = hh;
            hcI_s[4 * (ej >> 1) + 2 * eb + (ej & 1)] = hh;
            out[((size_t)t * B + bg) * H + ej] = h_new;
            const int lb = eb ? len1 : len0;
            if (t == lb - 1) {
                hfin[(size_t)bg * H + ej] = h_new;
                cfin[(size_t)bg * H + ej] = c_reg;
            }
        }
        BARL();  // H
    }
}

extern "C" void kernel_launch(void* const* d_in, const int* in_sizes, int n_in,
                              void* d_out, int out_size, void* d_ws, size_t ws_size,
                              hipStream_t stream) {
    const float* embs = (const float*)d_in[0];
    const int*   lens = (const int*)d_in[1];
    const float* Wih  = (const float*)d_in[2];
    const float* Whh  = (const float*)d_in[3];
    const float* bih  = (const float*)d_in[4];
    const float* bhh  = (const float*)d_in[5];
    const float* Wa   = (const float*)d_in[6];
    const float* ba   = (const float*)d_in[7];
    float* out = (float*)d_out;

    // ws layout: G fp32 [T*B][4H] (64 MB) | WhH half2[128*1024] (512 KB) | WaH half2[256*256] (256 KB)
    float* G      = (float*)d_ws;
    half2_t* WhH  = (half2_t*)(G + (size_t)T * B * G4);
    half2_t* WaH  = WhH + (size_t)128 * G4;

    pack_whH<<<128, G4, 0, stream>>>(Whh, WhH);
    pack_waH<<<256, H, 0, stream>>>(Wa, WaH);
    dim3 ggrid(T * B / 64, G4 / 64);
    gemm_g<<<ggrid, 256, 0, stream>>>(embs, Wih, bih, bhh, G);
    alstm6<<<B / NB, 1024, 0, stream>>>(lens, G, WhH, WaH, ba, out);
}

// Round 12
// 1891.255 us; speedup vs baseline: 5.5042x; 5.5042x over previous
//
#include <hip/hip_runtime.h>
#include <math.h>

#define T 128
#define B 128
#define H 256
#define I 256
#define G4 1024  // 4*H
#define NB 2     // batch elements per block

typedef unsigned short u16;
typedef unsigned int u32;
typedef _Float16 half_t;
typedef _Float16 half2_t __attribute__((ext_vector_type(2)));

#if defined(__has_builtin)
#if __has_builtin(__builtin_amdgcn_fdot2)
#define HAS_FDOT2 1
#endif
#endif

__device__ __forceinline__ float fdot2(half2_t a, half2_t b, float c) {
#ifdef HAS_FDOT2
    return __builtin_amdgcn_fdot2(a, b, c, false);
#else
    return fmaf((float)a.x, (float)b.x, fmaf((float)a.y, (float)b.y, c));
#endif
}
__device__ __forceinline__ half2_t h2cast(u32 u) { return __builtin_bit_cast(half2_t, u); }

__device__ __forceinline__ float sigmoid_fast(float x) {
    return 1.0f / (1.0f + __expf(-x));
}
__device__ __forceinline__ float tanh_fast(float x) {
    x = fminf(fmaxf(x, -15.f), 15.f);
    const float e = __expf(2.0f * x);
    return (e - 1.0f) / (e + 1.0f);
}

// LDS-only barrier: drain lgkmcnt (ds_write visibility) + s_barrier, but do NOT
// drain vmcnt — register-destined global loads stay in flight across phases.
// Correctness validated rounds 9-10 (absmax bit-identical). No sched_barrier
// (round-9 lesson), no manual prefetch arrays (round-10 scratch-spill lesson).
#define BARL() do {                                        \
    asm volatile("s_waitcnt lgkmcnt(0)" ::: "memory");     \
    __builtin_amdgcn_s_barrier();                          \
} while (0)

// ---------------- weight repack (one-shot, fp16 k-pair-major == coalesced) ----------------
// WhH[k2][o] = half2{Whh[o][2k2], Whh[o][2k2+1]},  k2<128, o<1024
__global__ void pack_whH(const float* __restrict__ Whh, half2_t* __restrict__ WhH) {
    const int k2 = blockIdx.x;      // 0..127
    const int o  = threadIdx.x;     // 0..1023
    half2_t v;
    v.x = (half_t)Whh[(size_t)o * H + 2 * k2];
    v.y = (half_t)Whh[(size_t)o * H + 2 * k2 + 1];
    WhH[(size_t)k2 * G4 + o] = v;
}
// WaH[k2][j] = half2{Wa[j][2k2], Wa[j][2k2+1]},  k2<256, j<256
__global__ void pack_waH(const float* __restrict__ Wa, half2_t* __restrict__ WaH) {
    const int k2 = blockIdx.x;      // 0..255
    const int j  = threadIdx.x;     // 0..255
    half2_t v;
    v.x = (half_t)Wa[(size_t)j * (2 * H) + 2 * k2];
    v.y = (half_t)Wa[(size_t)j * (2 * H) + 2 * k2 + 1];
    WaH[(size_t)k2 * H + j] = v;
}

// ---------------- G = embs @ Wih^T + bih + bhh ----------------
__global__ __launch_bounds__(256) void gemm_g(const float* __restrict__ A,
                                              const float* __restrict__ W,
                                              const float* __restrict__ bih,
                                              const float* __restrict__ bhh,
                                              float* __restrict__ G) {
    __shared__ __align__(16) float As[64][68];
    __shared__ __align__(16) float Ws[64][68];
    const int m0 = blockIdx.x * 64;
    const int n0 = blockIdx.y * 64;
    const int tid = threadIdx.x;
    const int ty = tid >> 4, tx = tid & 15;
    const int rr = tid >> 4;
    const int kr = tid & 15;

    float acc[4][4] = {};
    for (int k0 = 0; k0 < I; k0 += 64) {
#pragma unroll
        for (int i = 0; i < 4; ++i) {
            const int r = rr + 16 * i;
            const float4 av = *(const float4*)&A[(size_t)(m0 + r) * I + k0 + kr * 4];
            const float4 wv = *(const float4*)&W[(size_t)(n0 + r) * I + k0 + kr * 4];
            As[kr * 4 + 0][r] = av.x; As[kr * 4 + 1][r] = av.y;
            As[kr * 4 + 2][r] = av.z; As[kr * 4 + 3][r] = av.w;
            Ws[kr * 4 + 0][r] = wv.x; Ws[kr * 4 + 1][r] = wv.y;
            Ws[kr * 4 + 2][r] = wv.z; Ws[kr * 4 + 3][r] = wv.w;
        }
        __syncthreads();
#pragma unroll 8
        for (int kk = 0; kk < 64; ++kk) {
            const float4 a4 = *(const float4*)&As[kk][ty * 4];
            const float4 w4 = *(const float4*)&Ws[kk][tx * 4];
            const float a[4] = {a4.x, a4.y, a4.z, a4.w};
            const float w[4] = {w4.x, w4.y, w4.z, w4.w};
#pragma unroll
            for (int i = 0; i < 4; ++i)
#pragma unroll
                for (int jj = 0; jj < 4; ++jj)
                    acc[i][jj] = fmaf(a[i], w[jj], acc[i][jj]);
        }
        __syncthreads();
    }
    const int n = n0 + tx * 4;
    const float4 bi = *(const float4*)&bih[n];
    const float4 bh = *(const float4*)&bhh[n];
    const float4 bb = make_float4(bi.x + bh.x, bi.y + bh.y, bi.z + bh.z, bi.w + bh.w);
#pragma unroll
    for (int i = 0; i < 4; ++i) {
        const int m = m0 + ty * 4 + i;
        float4 o = make_float4(acc[i][0] + bb.x, acc[i][1] + bb.y,
                               acc[i][2] + bb.z, acc[i][3] + bb.w);
        *(float4*)&G[(size_t)m * G4 + n] = o;
    }
}

// ---------------- recurrent attention-LSTM: NB=2, fdot2, LDS-only barriers ----------------
// LDS: hid 131072 + sc 1024 + hH 1024 + hcI 2048 + hinI 1024 + red 8192 + gate 8192
//      = 152576 B <= 163840 (1 block/CU, 16 waves)
__global__ __launch_bounds__(1024, 4) void alstm7(
    const int* __restrict__ lens,
    const float* __restrict__ G,       // [T*B][4H]
    const half2_t* __restrict__ WhH,   // [128][1024] k2-major
    const half2_t* __restrict__ WaH,   // [256][256]  k2-major
    const float* __restrict__ ba,
    float* __restrict__ out)           // hs | h_fin | c_fin
{
    __shared__ __align__(16) half_t hid_s[NB][T][H];   // fp16 history, 128 KB
    __shared__ __align__(16) float  sc_s[NB][T];
    __shared__ __align__(16) half_t hH_s[NB][H];       // h (for scores)
    __shared__ __align__(16) half_t hcI_s[4 * 256];    // [h|ctx], batch-interleaved k-pairs
    __shared__ __align__(16) half_t hinI_s[4 * 128];   // hin, batch-interleaved k-pairs
    __shared__ __align__(16) float  red_s[2048];       // phase-reuse reduce buffer
    __shared__ __align__(16) float  gate_s[NB][G4];    // prefetched G rows

    const int b0 = blockIdx.x * NB;
    const int tid = threadIdx.x;
    const int lane = tid & 63;
    const int wave = tid >> 6;        // 0..15
    const int sb = wave >> 3;         // scores batch
    const int stp0 = wave & 7;        // scores t'-stride id
    const int cb = tid >> 9;          // ctx batch
    const int ck = (tid >> 8) & 1;    // ctx 2-way t-split
    const int cj = tid & 255;         // ctx feature
    const int ako = tid >> 8;         // Wa k-chunk 0..3
    const int aj = tid & 255;         // Wa output j
    const int eb = tid >> 8;          // cell batch (valid under tid<512)
    const int ej = tid & 255;         // cell feature

    const int len0 = lens[b0], len1 = lens[b0 + 1];
    float c_reg = 0.f;
    float* hfin = out + (size_t)T * B * H;
    float* cfin = hfin + (size_t)B * H;
    if (tid < 512) hH_s[eb][ej] = (half_t)0.f;
    BARL();

    for (int t = 0; t < T; ++t) {
        // G-row loads issue here; consumed at the gate stash (P2) — several
        // phases of latency hiding since BARL never drains vmcnt.
        const float gA = G[((size_t)t * B + b0) * G4 + tid];
        const float gB = G[((size_t)t * B + b0 + 1) * G4 + tid];

        if (t > 0) {
            // ---- P0: scores (8 waves per batch, t' strided) ----
            {
                const half2_t h2a = h2cast(*(const u32*)&hH_s[sb][lane * 4]);
                const half2_t h2b = h2cast(*(const u32*)&hH_s[sb][lane * 4 + 2]);
                for (int tp = stp0; tp < t; tp += 8) {
                    const uint2 hv = *(const uint2*)&hid_s[sb][tp][lane * 4];
                    float d = fdot2(h2cast(hv.x), h2a, fdot2(h2cast(hv.y), h2b, 0.f));
#pragma unroll
                    for (int off = 32; off; off >>= 1) d += __shfl_xor(d, off);
                    if (lane == 0) sc_s[sb][tp] = d;
                }
            }
            BARL();  // A
            // ---- P1: softmax (wave 0 -> batch 0, wave 8 -> batch 1) ----
            if (stp0 == 0) {
                const float v0 = (lane < t) ? sc_s[sb][lane] : -3.0e38f;
                const float v1 = (lane + 64 < t) ? sc_s[sb][lane + 64] : -3.0e38f;
                float m = fmaxf(v0, v1);
#pragma unroll
                for (int off = 32; off; off >>= 1) m = fmaxf(m, __shfl_xor(m, off));
                const float e0 = (lane < t) ? __expf(v0 - m) : 0.f;
                const float e1 = (lane + 64 < t) ? __expf(v1 - m) : 0.f;
                float s = e0 + e1;
#pragma unroll
                for (int off = 32; off; off >>= 1) s += __shfl_xor(s, off);
                const float inv = 1.f / s;
                if (lane < t) sc_s[sb][lane] = e0 * inv;
                if (lane + 64 < t) sc_s[sb][lane + 64] = e1 * inv;
            }
            BARL();  // B
            // ---- P2: ctx partials (2-way t-split per batch) + G stash ----
            {
                float cacc = 0.f;
                for (int tp = ck; tp < t; tp += 2)
                    cacc = fmaf(sc_s[cb][tp], (float)hid_s[cb][tp][cj], cacc);
                red_s[cb * 512 + ck * 256 + cj] = cacc;
                gate_s[0][tid] = gA;
                gate_s[1][tid] = gB;
            }
            BARL();  // C
            // ---- P3a: ctx reduce -> hcI ctx half ----
            if (tid < 512) {
                const float ctxv = red_s[eb * 512 + ej] + red_s[eb * 512 + 256 + ej];
                hcI_s[512 + 4 * (ej >> 1) + 2 * eb + (ej & 1)] = (half_t)ctxv;
            }
            BARL();  // D
            // ---- P3: Wa GEMV (fdot2, coalesced shared weight stream) ----
            {
                const half2_t* wp = &WaH[(size_t)(ako * 64) * H + aj];
                float a0 = 0.f, a1 = 0.f;
#pragma unroll 8
                for (int kk = 0; kk < 64; ++kk) {
                    const int k2 = ako * 64 + kk;
                    const uint2 hh = *(const uint2*)&hcI_s[4 * k2];
                    const half2_t w = wp[(size_t)kk * H];
                    a0 = fdot2(w, h2cast(hh.x), a0);
                    a1 = fdot2(w, h2cast(hh.y), a1);
                }
                red_s[ako * 512 + aj] = a0;
                red_s[ako * 512 + 256 + aj] = a1;
            }
            BARL();  // E
            // ---- P4: hin reduce + tanh ----
            if (tid < 512) {
                float a = ba[ej];
#pragma unroll
                for (int r = 0; r < 4; ++r) a += red_s[r * 512 + eb * 256 + ej];
                hinI_s[4 * (ej >> 1) + 2 * eb + (ej & 1)] = (half_t)tanh_fast(a);
            }
            BARL();  // F
            // ---- P5: Whh GEMV (one output o=tid, both batches, fdot2) ----
            {
                const half2_t* wp = &WhH[tid];
                float g0 = 0.f, g1 = 0.f;
#pragma unroll 8
                for (int k2 = 0; k2 < 128; ++k2) {
                    const uint2 hh = *(const uint2*)&hinI_s[4 * k2];
                    const half2_t w = wp[(size_t)k2 * G4];
                    g0 = fdot2(w, h2cast(hh.x), g0);
                    g1 = fdot2(w, h2cast(hh.y), g1);
                }
                red_s[tid] = g0;
                red_s[1024 + tid] = g1;
            }
        } else {
            // t == 0: h_in = 0 -> recurrent contribution is exactly 0
            gate_s[0][tid] = gA;
            gate_s[1][tid] = gB;
            red_s[tid] = 0.f;
            red_s[1024 + tid] = 0.f;
        }
        BARL();  // G
        // ---- P6: gate sum + cell update (threads 0..511) ----
        if (tid < 512) {
            const int bg = b0 + eb;
            const float gi = gate_s[eb][ej]         + red_s[eb * 1024 + ej];
            const float gf = gate_s[eb][H + ej]     + red_s[eb * 1024 + H + ej];
            const float gg = gate_s[eb][2 * H + ej] + red_s[eb * 1024 + 2 * H + ej];
            const float go = gate_s[eb][3 * H + ej] + red_s[eb * 1024 + 3 * H + ej];
            const float ig = sigmoid_fast(gi);
            const float fg = sigmoid_fast(gf);
            const float gv = tanh_fast(gg);
            const float og = sigmoid_fast(go);
            c_reg = fmaf(fg, c_reg, ig * gv);
            const float h_new = og * tanh_fast(c_reg);
            const half_t hh = (half_t)h_new;
            hH_s[eb][ej] = hh;
            hid_s[eb][t][ej] = hh;
            hcI_s[4 * (ej >> 1) + 2 * eb + (ej & 1)] = hh;
            out[((size_t)t * B + bg) * H + ej] = h_new;
            const int lb = eb ? len1 : len0;
            if (t == lb - 1) {
                hfin[(size_t)bg * H + ej] = h_new;
                cfin[(size_t)bg * H + ej] = c_reg;
            }
        }
        BARL();  // H
    }
}

extern "C" void kernel_launch(void* const* d_in, const int* in_sizes, int n_in,
                              void* d_out, int out_size, void* d_ws, size_t ws_size,
                              hipStream_t stream) {
    const float* embs = (const float*)d_in[0];
    const int*   lens = (const int*)d_in[1];
    const float* Wih  = (const float*)d_in[2];
    const float* Whh  = (const float*)d_in[3];
    const float* bih  = (const float*)d_in[4];
    const float* bhh  = (const float*)d_in[5];
    const float* Wa   = (const float*)d_in[6];
    const float* ba   = (const float*)d_in[7];
    float* out = (float*)d_out;

    // ws layout: G fp32 [T*B][4H] (64 MB) | WhH half2[128*1024] (512 KB) | WaH half2[256*256] (256 KB)
    float* G      = (float*)d_ws;
    half2_t* WhH  = (half2_t*)(G + (size_t)T * B * G4);
    half2_t* WaH  = WhH + (size_t)128 * G4;

    pack_whH<<<128, G4, 0, stream>>>(Whh, WhH);
    pack_waH<<<256, H, 0, stream>>>(Wa, WaH);
    dim3 ggrid(T * B / 64, G4 / 64);
    gemm_g<<<ggrid, 256, 0, stream>>>(embs, Wih, bih, bhh, G);
    alstm7<<<B / NB, 1024, 0, stream>>>(lens, G, WhH, WaH, ba, out);
}